// Round 6
// baseline (213.605 us; speedup 1.0000x reference)
//
#include <hip/hip_runtime.h>

// Problem constants (B=8, C=256, H=W=128, L=512)
#define BATCH 8
#define CIN   256
#define LDIM  512
#define HDIM  128
#define WDIM  128
#define HWN   (HDIM * WDIM)      // 16384
#define PH    64                  // prev_rgb spatial
#define PW    64

// ---------------------------------------------------------------------------
// Kernel 1: style = istyle @ style_w.T + style_b ; wmod[b,o,c] = conv_w[o,c]*(style+1)
// grid = BATCH*CIN blocks of 64 threads (1 wave each). Coalesced over L.
// ---------------------------------------------------------------------------
__global__ __launch_bounds__(64)
void style_weights_kernel(const float* __restrict__ istyle,   // [B, L]
                          const float* __restrict__ style_w,  // [C, L]
                          const float* __restrict__ style_b,  // [C]
                          const float* __restrict__ conv_w,   // [3, C]
                          float* __restrict__ wmod) {         // [B, 3, C]
    const int bid = blockIdx.x;          // 0 .. B*C-1
    const int b = bid >> 8;              // bid / CIN
    const int c = bid & (CIN - 1);
    const int t = threadIdx.x;           // 0..63

    const float* is = istyle + b * LDIM;
    const float* sw = style_w + c * LDIM;

    float p = 0.0f;
#pragma unroll
    for (int l = t; l < LDIM; l += 64) p += is[l] * sw[l];

    // wave64 butterfly reduce
#pragma unroll
    for (int off = 32; off > 0; off >>= 1) p += __shfl_down(p, off);

    if (t == 0) {
        const float s = p + style_b[c] + 1.0f;
        wmod[(b * 3 + 0) * CIN + c] = conv_w[0 * CIN + c] * s;
        wmod[(b * 3 + 1) * CIN + c] = conv_w[1 * CIN + c] * s;
        wmod[(b * 3 + 2) * CIN + c] = conv_w[2 * CIN + c] * s;
    }
}

// ---------------------------------------------------------------------------
// Kernel 2: out[b,o,pos] = sum_c wmod[b,o,c]*x[b,c,pos] + rgb_bias[o] + upsample
// Single-wave blocks (64 thr), 4 positions per thread via float4 loads.
// 256 pos/block (1 KiB contiguous per c-plane) -> grid = 512 blocks = 2/CU.
// ---------------------------------------------------------------------------
__global__ __launch_bounds__(64)
void rgb_main_kernel(const float* __restrict__ x,        // [B, C, H, W]
                     const float* __restrict__ prev,     // [B, 3, 64, 64]
                     const float* __restrict__ rgb_bias, // [3]
                     const float* __restrict__ wmod,     // [B, 3, C]
                     float* __restrict__ out) {          // [B, 3, H, W]
    __shared__ float sw[3 * CIN];

    const int t    = threadIdx.x;                 // 0..63
    const int flat = blockIdx.x * 256;            // 256 pos per block; 256 | 16384
    const int b    = flat >> 14;                  // flat / HWN
    const int pos  = (flat & (HWN - 1)) + t * 4;  // 4-aligned spatial position

    // stage this batch's 768 modulated weights into LDS (12 loads/lane)
#pragma unroll
    for (int i = t; i < 3 * CIN; i += 64)
        sw[i] = wmod[b * 3 * CIN + i];
    __syncthreads();

    const float4* xp = (const float4*)(x + ((size_t)b * CIN) * HWN + pos);

    float a0[4] = {0.f, 0.f, 0.f, 0.f};
    float a1[4] = {0.f, 0.f, 0.f, 0.f};
    float a2[4] = {0.f, 0.f, 0.f, 0.f};
#pragma unroll 8
    for (int c = 0; c < CIN; ++c) {
        const float4 v = xp[(size_t)c * (HWN / 4)];  // 1 KiB per wave-instr
        const float w0 = sw[c];                      // LDS same-address broadcast
        const float w1 = sw[CIN + c];
        const float w2 = sw[2 * CIN + c];
        a0[0] += v.x * w0; a0[1] += v.y * w0; a0[2] += v.z * w0; a0[3] += v.w * w0;
        a1[0] += v.x * w1; a1[1] += v.y * w1; a1[2] += v.z * w1; a1[3] += v.w * w1;
        a2[0] += v.x * w2; a2[1] += v.y * w2; a2[2] += v.z * w2; a2[3] += v.w * w2;
    }

    // --- bilinear x2 upsample, half-pixel centers, edge clamp (4 pixels) ---
    const int h = pos >> 7;
    const float shf = h * 0.5f - 0.25f;
    const float fh  = shf - floorf(shf);     // 0.25 or 0.75
    int h0 = (int)floorf(shf);
    int h1 = min(h0 + 1, PH - 1);
    h0 = max(h0, 0);

    const float* pb = prev + (size_t)b * 3 * PH * PW;
    float up[3][4];
#pragma unroll
    for (int j = 0; j < 3 * 4; ++j) {
        const int o  = j >> 2;
        const int jj = j & 3;
        const int w  = (pos & (WDIM - 1)) + jj;
        // w = 2k   -> w0 = k-1 (clamp), fw = 0.75
        // w = 2k+1 -> w0 = k,   w1 = k+1 (clamp), fw = 0.25
        const int k  = w >> 1;
        const bool odd = (w & 1) != 0;
        const int w0i = odd ? k : max(k - 1, 0);
        const int w1i = odd ? min(k + 1, PW - 1) : k;
        const float fw = odd ? 0.25f : 0.75f;

        const float* p0 = pb + o * PH * PW + h0 * PW;
        const float* p1 = pb + o * PH * PW + h1 * PW;
        const float top = p0[w0i] + (p0[w1i] - p0[w0i]) * fw;
        const float bot = p1[w0i] + (p1[w1i] - p1[w0i]) * fw;
        up[o][jj] = top + (bot - top) * fh;
    }

    float4* op = (float4*)(out + ((size_t)b * 3) * HWN + pos);
    const float b0 = rgb_bias[0], b1 = rgb_bias[1], b2 = rgb_bias[2];
    op[0] = make_float4(a0[0] + b0 + up[0][0], a0[1] + b0 + up[0][1],
                        a0[2] + b0 + up[0][2], a0[3] + b0 + up[0][3]);
    op[HWN / 4] = make_float4(a1[0] + b1 + up[1][0], a1[1] + b1 + up[1][1],
                              a1[2] + b1 + up[1][2], a1[3] + b1 + up[1][3]);
    op[HWN / 2] = make_float4(a2[0] + b2 + up[2][0], a2[1] + b2 + up[2][1],
                              a2[2] + b2 + up[2][2], a2[3] + b2 + up[2][3]);
}

// ---------------------------------------------------------------------------
extern "C" void kernel_launch(void* const* d_in, const int* in_sizes, int n_in,
                              void* d_out, int out_size, void* d_ws, size_t ws_size,
                              hipStream_t stream) {
    const float* x        = (const float*)d_in[0];  // [8,256,128,128]
    const float* prev_rgb = (const float*)d_in[1];  // [8,3,64,64]
    const float* istyle   = (const float*)d_in[2];  // [8,512]
    const float* style_w  = (const float*)d_in[3];  // [256,512]
    const float* style_b  = (const float*)d_in[4];  // [256]
    const float* conv_w   = (const float*)d_in[5];  // [3,256]
    const float* rgb_bias = (const float*)d_in[6];  // [3]
    float* out = (float*)d_out;
    float* wmod = (float*)d_ws;                     // [8,3,256] = 24 KB

    style_weights_kernel<<<BATCH * CIN, 64, 0, stream>>>(
        istyle, style_w, style_b, conv_w, wmod);

    rgb_main_kernel<<<(BATCH * HWN) / 256, 64, 0, stream>>>(
        x, prev_rgb, rgb_bias, wmod, out);
}